// Round 2
// baseline (1711.876 us; speedup 1.0000x reference)
//
#include <hip/hip_runtime.h>

typedef _Float16 half2_t __attribute__((ext_vector_type(2)));

constexpr int D = 256;
constexpr int NUTT = 64;
constexpr int L = 512;
constexpr int G = 768;           // 3*D
constexpr int KREG = 112;        // half2 pairs per gate-row held in VGPRs (k < 224)
constexpr int KLDS = 16;         // half2 pairs per gate-row held in LDS (k in [224,256))

__device__ __forceinline__ half2_t u2h(unsigned int u) {
  return __builtin_bit_cast(half2_t, u);
}
__device__ __forceinline__ unsigned int pack2(float a, float b) {
  half2_t h{(_Float16)a, (_Float16)b};
  return __builtin_bit_cast(unsigned int, h);
}

__device__ __forceinline__ float fdot2(half2_t a, half2_t b, float c) {
#if defined(__has_builtin)
#if __has_builtin(__builtin_amdgcn_fdot2)
  return __builtin_amdgcn_fdot2(a, b, c, false);
#else
  return c + (float)a.x * (float)b.x + (float)a.y * (float)b.y;
#endif
#else
  return c + (float)a.x * (float)b.x + (float)a.y * (float)b.y;
#endif
}

__device__ __forceinline__ float sigm(float x) {
  return 1.0f / (1.0f + __expf(-x));
}
__device__ __forceinline__ float tanh_f(float x) {
  float ax = fabsf(x);
  float e = __expf(-2.0f * ax);
  float r = (1.0f - e) / (1.0f + e);
  return copysignf(r, x);
}

// ---------------------------------------------------------------------------
// Kernel B: gx[m][g] = embed[tokens[m]][:] . Wih[g][:] + bih[g]
// m = b*L + t  (M = 32768), g in [0,768).  Tiled fp32 GEMM, BM=64 BN=128 BK=32
// ---------------------------------------------------------------------------
__global__ __launch_bounds__(256) void gx_gemm(
    const int* __restrict__ tokens, const float* __restrict__ embed,
    const float* __restrict__ Wih, const float* __restrict__ bih,
    float* __restrict__ gx) {
  __shared__ float As[64][33];
  __shared__ float Bs[32][129];
  __shared__ int toks[64];

  const int tid = threadIdx.x;
  const int m0 = blockIdx.x * 64;
  const int n0 = blockIdx.y * 128;
  if (tid < 64) toks[tid] = tokens[m0 + tid];
  __syncthreads();

  const int ty = tid >> 4;   // 0..15 : row group (4 rows each)
  const int tx = tid & 15;   // 0..15 : col base (cols tx + 16*cc)
  float acc[4][8] = {};

  for (int k0 = 0; k0 < 256; k0 += 32) {
    // stage A (embedding gather rows)
    {
      const int i = tid >> 2;            // 0..63
      const int kq = (tid & 3) * 4;      // 0,4,8,12
      const float* src = embed + (size_t)toks[i] * D + k0;
      float4 v0 = *(const float4*)(src + kq);
      float4 v1 = *(const float4*)(src + kq + 16);
      As[i][kq + 0] = v0.x; As[i][kq + 1] = v0.y;
      As[i][kq + 2] = v0.z; As[i][kq + 3] = v0.w;
      As[i][kq + 16] = v1.x; As[i][kq + 17] = v1.y;
      As[i][kq + 18] = v1.z; As[i][kq + 19] = v1.w;
    }
    // stage B (weights, transposed into [k][g])
    {
      const int goff = tid >> 3;         // 0..31
      const int kq = (tid & 7) * 4;      // 0..28
      for (int gp = 0; gp < 128; gp += 32) {
        const float* src = Wih + (size_t)(n0 + goff + gp) * D + k0 + kq;
        float4 v = *(const float4*)src;
        Bs[kq + 0][goff + gp] = v.x;
        Bs[kq + 1][goff + gp] = v.y;
        Bs[kq + 2][goff + gp] = v.z;
        Bs[kq + 3][goff + gp] = v.w;
      }
    }
    __syncthreads();
    const int r0 = ty * 4;
#pragma unroll 4
    for (int k = 0; k < 32; ++k) {
      float a0 = As[r0 + 0][k], a1 = As[r0 + 1][k];
      float a2 = As[r0 + 2][k], a3 = As[r0 + 3][k];
#pragma unroll
      for (int cc = 0; cc < 8; ++cc) {
        float bv = Bs[k][tx + 16 * cc];
        acc[0][cc] = fmaf(a0, bv, acc[0][cc]);
        acc[1][cc] = fmaf(a1, bv, acc[1][cc]);
        acc[2][cc] = fmaf(a2, bv, acc[2][cc]);
        acc[3][cc] = fmaf(a3, bv, acc[3][cc]);
      }
    }
    __syncthreads();
  }
#pragma unroll
  for (int rr = 0; rr < 4; ++rr) {
    float* dst = gx + (size_t)(m0 + ty * 4 + rr) * G + n0;
#pragma unroll
    for (int cc = 0; cc < 8; ++cc) {
      int c = tx + 16 * cc;
      dst[c] = acc[rr][cc] + bih[n0 + c];
    }
  }
}

// ---------------------------------------------------------------------------
// Kernel C: persistent word-GRU scan. 64 WGs x 256 threads (4 waves, 1/SIMD).
// Thread d owns gate rows d (r), D+d (z), 2D+d (n) of W_hh:
//   3 x 112 half2 in VGPRs (unified VGPR/AGPR file, 1 wave/SIMD => 512 regs)
//   3 x 16 half2 tail in LDS, packed as uint4 per (gate, chunk, thread).
// Per step: one f16 h-vector broadcast from LDS feeds all 3 gate dots;
// r/z/n pre-activations stay in registers (no pre[] round-trip);
// h double-buffered in LDS => ONE barrier per step.
// ---------------------------------------------------------------------------
__global__ __launch_bounds__(256, 1) void gru_scan_word(
    const float* __restrict__ gx,    // [NUTT][L][G] (includes b_ih)
    const float* __restrict__ Whh,   // [G][D]
    const float* __restrict__ bhh,   // [G]
    float* __restrict__ wo) {        // [NUTT][L][D]
  __shared__ __align__(16) half2_t h2s[2][D / 2];          // 2 KB
  __shared__ uint4 wtail[3][KLDS / 4][D];                  // 48 KB

  const int d = threadIdx.x;
  const int b = blockIdx.x;

  // --- load this thread's three gate rows ---
  half2_t wr[KREG], wz[KREG], wn[KREG];
  {
    const float* rowR = Whh + (size_t)d * D;
    const float* rowZ = Whh + (size_t)(D + d) * D;
    const float* rowN = Whh + (size_t)(2 * D + d) * D;
#pragma unroll
    for (int c = 0; c < KREG / 2; ++c) {
      float4 v = *(const float4*)(rowR + 4 * c);
      wr[2 * c]     = half2_t{(_Float16)v.x, (_Float16)v.y};
      wr[2 * c + 1] = half2_t{(_Float16)v.z, (_Float16)v.w};
      v = *(const float4*)(rowZ + 4 * c);
      wz[2 * c]     = half2_t{(_Float16)v.x, (_Float16)v.y};
      wz[2 * c + 1] = half2_t{(_Float16)v.z, (_Float16)v.w};
      v = *(const float4*)(rowN + 4 * c);
      wn[2 * c]     = half2_t{(_Float16)v.x, (_Float16)v.y};
      wn[2 * c + 1] = half2_t{(_Float16)v.z, (_Float16)v.w};
    }
    // tails into LDS, packed 4 half2 = 16B per (gate, chunk, thread)
    const float* rows[3] = {rowR, rowZ, rowN};
#pragma unroll
    for (int q = 0; q < 3; ++q) {
#pragma unroll
      for (int c = 0; c < KLDS / 4; ++c) {
        const float* src = rows[q] + 2 * KREG + 8 * c;
        float4 v0 = *(const float4*)src;
        float4 v1 = *(const float4*)(src + 4);
        uint4 p;
        p.x = pack2(v0.x, v0.y);
        p.y = pack2(v0.z, v0.w);
        p.z = pack2(v1.x, v1.y);
        p.w = pack2(v1.z, v1.w);
        wtail[q][c][d] = p;
      }
    }
  }
  const float bR = bhh[d];
  const float bZ = bhh[D + d];
  const float bN = bhh[2 * D + d];
  if (d < D / 2) h2s[0][d] = half2_t{(_Float16)0.0f, (_Float16)0.0f};

  const float* gxb = gx + (size_t)b * L * G;
  float gr = gxb[d];
  float gz = gxb[D + d];
  float gn = gxb[2 * D + d];
  float hprev = 0.0f;
  float* wob = wo + (size_t)b * L * D;
  __syncthreads();

  for (int t = 0; t < L; ++t) {
    const int cur = t & 1;
    // prefetch next step's gx
    const int tn = (t + 1 < L) ? t + 1 : t;
    const float* gxn_p = gxb + (size_t)tn * G;
    float gr2 = gxn_p[d];
    float gz2 = gxn_p[D + d];
    float gn2 = gxn_p[2 * D + d];

    const uint4* hv = reinterpret_cast<const uint4*>(h2s[cur]);
    float aR0 = 0.0f, aR1 = 0.0f;
    float aZ0 = 0.0f, aZ1 = 0.0f;
    float aN0 = 0.0f, aN1 = 0.0f;
#pragma unroll
    for (int c = 0; c < KREG / 4; ++c) {       // 28 chunks: 1 b128 broadcast -> 12 dot2
      uint4 v = hv[c];
      half2_t h0 = u2h(v.x), h1 = u2h(v.y), h2 = u2h(v.z), h3 = u2h(v.w);
      aR0 = fdot2(wr[4 * c + 0], h0, aR0);
      aR1 = fdot2(wr[4 * c + 1], h1, aR1);
      aR0 = fdot2(wr[4 * c + 2], h2, aR0);
      aR1 = fdot2(wr[4 * c + 3], h3, aR1);
      aZ0 = fdot2(wz[4 * c + 0], h0, aZ0);
      aZ1 = fdot2(wz[4 * c + 1], h1, aZ1);
      aZ0 = fdot2(wz[4 * c + 2], h2, aZ0);
      aZ1 = fdot2(wz[4 * c + 3], h3, aZ1);
      aN0 = fdot2(wn[4 * c + 0], h0, aN0);
      aN1 = fdot2(wn[4 * c + 1], h1, aN1);
      aN0 = fdot2(wn[4 * c + 2], h2, aN0);
      aN1 = fdot2(wn[4 * c + 3], h3, aN1);
    }
#pragma unroll
    for (int c = 0; c < KLDS / 4; ++c) {       // LDS-resident weight tail
      uint4 v = hv[KREG / 4 + c];
      half2_t h0 = u2h(v.x), h1 = u2h(v.y), h2 = u2h(v.z), h3 = u2h(v.w);
      uint4 wR = wtail[0][c][d];
      uint4 wZ = wtail[1][c][d];
      uint4 wN = wtail[2][c][d];
      aR0 = fdot2(u2h(wR.x), h0, aR0);
      aR1 = fdot2(u2h(wR.y), h1, aR1);
      aR0 = fdot2(u2h(wR.z), h2, aR0);
      aR1 = fdot2(u2h(wR.w), h3, aR1);
      aZ0 = fdot2(u2h(wZ.x), h0, aZ0);
      aZ1 = fdot2(u2h(wZ.y), h1, aZ1);
      aZ0 = fdot2(u2h(wZ.z), h2, aZ0);
      aZ1 = fdot2(u2h(wZ.w), h3, aZ1);
      aN0 = fdot2(u2h(wN.x), h0, aN0);
      aN1 = fdot2(u2h(wN.y), h1, aN1);
      aN0 = fdot2(u2h(wN.z), h2, aN0);
      aN1 = fdot2(u2h(wN.w), h3, aN1);
    }

    float r = sigm(gr + aR0 + aR1 + bR);
    float z = sigm(gz + aZ0 + aZ1 + bZ);
    float n = tanh_f(gn + r * (aN0 + aN1 + bN));
    float hn = fmaf(z, hprev - n, n);          // (1-z)*n + z*h
    hprev = hn;
    reinterpret_cast<_Float16*>(h2s[cur ^ 1])[d] = (_Float16)hn;
    wob[(size_t)t * D + d] = hn;
    gr = gr2; gz = gz2; gn = gn2;
    __syncthreads();
  }
}

// ---------------------------------------------------------------------------
// Kernel D: attention pool over word_out -> utt[64][256]
// ---------------------------------------------------------------------------
__global__ __launch_bounds__(256) void attn_pool_word(
    const float* __restrict__ wo, const float* __restrict__ uaw,
    float* __restrict__ utt) {
  __shared__ float wsh[D];
  __shared__ float lg[L];
  __shared__ float red[8];
  const int tid = threadIdx.x, b = blockIdx.x;
  wsh[tid] = uaw[tid];
  __syncthreads();

  const int wid = tid >> 6, lane = tid & 63;
  const float* base = wo + (size_t)b * L * D;
  for (int t = wid; t < L; t += 4) {
    const float* row = base + (size_t)t * D;
    float p = 0.0f;
#pragma unroll
    for (int j = 0; j < 4; ++j) p = fmaf(row[lane + 64 * j], wsh[lane + 64 * j], p);
#pragma unroll
    for (int off = 32; off; off >>= 1) p += __shfl_down(p, off);
    if (lane == 0) lg[t] = p;                  // ua_b cancels in softmax
  }
  __syncthreads();

  float m = fmaxf(lg[tid], lg[tid + 256]);
#pragma unroll
  for (int off = 32; off; off >>= 1) m = fmaxf(m, __shfl_down(m, off));
  if (lane == 0) red[wid] = m;
  __syncthreads();
  m = fmaxf(fmaxf(red[0], red[1]), fmaxf(red[2], red[3]));

  float e0 = __expf(lg[tid] - m), e1 = __expf(lg[tid + 256] - m);
  float s = e0 + e1;
#pragma unroll
  for (int off = 32; off; off >>= 1) s += __shfl_down(s, off);
  if (lane == 0) red[4 + wid] = s;
  __syncthreads();
  s = red[4] + red[5] + red[6] + red[7];
  float inv = 1.0f / s;
  lg[tid] = e0 * inv;
  lg[tid + 256] = e1 * inv;
  __syncthreads();

  float acc = 0.0f;
#pragma unroll 4
  for (int t = 0; t < L; ++t) acc = fmaf(lg[t], base[(size_t)t * D + tid], acc);
  utt[(size_t)b * D + tid] = acc;
}

// ---------------------------------------------------------------------------
// Kernel E: sentence GRU (T=1, h0=0) -> dialog_vec = (1-z)*n
// ---------------------------------------------------------------------------
__global__ __launch_bounds__(256) void sent_kernel(
    const float* __restrict__ utt, const float* __restrict__ Wih,
    const float* __restrict__ bih, const float* __restrict__ bhh,
    float* __restrict__ out) {
  __shared__ float u[D];
  const int d = threadIdx.x, b = blockIdx.x;
  u[d] = utt[(size_t)b * D + d];
  __syncthreads();

  const float* wr = Wih + (size_t)d * D;
  const float* wz = Wih + (size_t)(D + d) * D;
  const float* wn = Wih + (size_t)(2 * D + d) * D;
  float ar = 0.0f, az = 0.0f, an = 0.0f;
  for (int k = 0; k < D; k += 4) {
    float4 vr = *(const float4*)(wr + k);
    float4 vz = *(const float4*)(wz + k);
    float4 vn = *(const float4*)(wn + k);
    float u0 = u[k], u1 = u[k + 1], u2 = u[k + 2], u3 = u[k + 3];
    ar += vr.x * u0 + vr.y * u1 + vr.z * u2 + vr.w * u3;
    az += vz.x * u0 + vz.y * u1 + vz.z * u2 + vz.w * u3;
    an += vn.x * u0 + vn.y * u1 + vn.z * u2 + vn.w * u3;
  }
  float xr = ar + bih[d];
  float xz = az + bih[D + d];
  float xn = an + bih[2 * D + d];
  float r = sigm(xr + bhh[d]);
  float z = sigm(xz + bhh[D + d]);
  float n = tanh_f(xn + r * bhh[2 * D + d]);
  out[(size_t)b * D + d] = (1.0f - z) * n;
}

// ---------------------------------------------------------------------------
extern "C" void kernel_launch(void* const* d_in, const int* in_sizes, int n_in,
                              void* d_out, int out_size, void* d_ws, size_t ws_size,
                              hipStream_t stream) {
  const int* tokens    = (const int*)d_in[0];
  const float* embed   = (const float*)d_in[1];
  const float* wg_Wih  = (const float*)d_in[2];
  const float* wg_Whh  = (const float*)d_in[3];
  const float* wg_bih  = (const float*)d_in[4];
  const float* wg_bhh  = (const float*)d_in[5];
  const float* ua_w    = (const float*)d_in[6];
  // d_in[7] ua_b: softmax shift-invariant -> unused
  const float* sg_Wih  = (const float*)d_in[8];
  // d_in[9] sg_Whh: h0 == 0 -> unused
  const float* sg_bih  = (const float*)d_in[10];
  const float* sg_bhh  = (const float*)d_in[11];
  // d_in[12..13] da_w/da_b: softmax over T=1 -> unused
  float* out = (float*)d_out;

  char* ws = (char*)d_ws;
  float* gx  = (float*)ws;                                     // 96 MB
  float* wo  = (float*)(ws + (size_t)NUTT * L * G * 4);        // 32 MB
  float* utt = (float*)(ws + (size_t)NUTT * L * G * 4
                           + (size_t)NUTT * L * D * 4);        // 64 KB

  dim3 gB(512, 6);
  gx_gemm<<<gB, 256, 0, stream>>>(tokens, embed, wg_Wih, wg_bih, gx);
  gru_scan_word<<<NUTT, D, 0, stream>>>(gx, wg_Whh, wg_bhh, wo);
  attn_pool_word<<<NUTT, 256, 0, stream>>>(wo, ua_w, utt);
  sent_kernel<<<NUTT, 256, 0, stream>>>(utt, sg_Wih, sg_bih, sg_bhh, out);
}

// Round 3
// 995.016 us; speedup vs baseline: 1.7205x; 1.7205x over previous
//
#include <hip/hip_runtime.h>

typedef _Float16 half2_t __attribute__((ext_vector_type(2)));

constexpr int D = 256;
constexpr int NUTT = 64;
constexpr int L = 512;
constexpr int G = 768;           // 3*D

__device__ __forceinline__ half2_t u2h(unsigned int u) {
  return __builtin_bit_cast(half2_t, u);
}

__device__ __forceinline__ float fdot2(half2_t a, half2_t b, float c) {
#if defined(__has_builtin)
#if __has_builtin(__builtin_amdgcn_fdot2)
  return __builtin_amdgcn_fdot2(a, b, c, false);
#else
  return c + (float)a.x * (float)b.x + (float)a.y * (float)b.y;
#endif
#else
  return c + (float)a.x * (float)b.x + (float)a.y * (float)b.y;
#endif
}

// LDS-only barrier: orders ds_* ops across the workgroup WITHOUT draining
// vmcnt — global prefetch loads / wo stores stay in flight across steps.
__device__ __forceinline__ void lds_barrier() {
  asm volatile("s_waitcnt lgkmcnt(0)\n\ts_barrier" ::: "memory");
}

__device__ __forceinline__ float sigm(float x) {
  return 1.0f / (1.0f + __expf(-x));
}
__device__ __forceinline__ float tanh_f(float x) {
  float ax = fabsf(x);
  float e = __expf(-2.0f * ax);
  float r = (1.0f - e) / (1.0f + e);
  return copysignf(r, x);
}

// ---------------------------------------------------------------------------
// Kernel B: gx[m][g] = embed[tokens[m]][:] . Wih[g][:] + bih[g]
// m = b*L + t  (M = 32768), g in [0,768).  Tiled fp32 GEMM, BM=64 BN=128 BK=32
// ---------------------------------------------------------------------------
__global__ __launch_bounds__(256) void gx_gemm(
    const int* __restrict__ tokens, const float* __restrict__ embed,
    const float* __restrict__ Wih, const float* __restrict__ bih,
    float* __restrict__ gx) {
  __shared__ float As[64][33];
  __shared__ float Bs[32][129];
  __shared__ int toks[64];

  const int tid = threadIdx.x;
  const int m0 = blockIdx.x * 64;
  const int n0 = blockIdx.y * 128;
  if (tid < 64) toks[tid] = tokens[m0 + tid];
  __syncthreads();

  const int ty = tid >> 4;   // 0..15 : row group (4 rows each)
  const int tx = tid & 15;   // 0..15 : col base (cols tx + 16*cc)
  float acc[4][8] = {};

  for (int k0 = 0; k0 < 256; k0 += 32) {
    // stage A (embedding gather rows)
    {
      const int i = tid >> 2;            // 0..63
      const int kq = (tid & 3) * 4;      // 0,4,8,12
      const float* src = embed + (size_t)toks[i] * D + k0;
      float4 v0 = *(const float4*)(src + kq);
      float4 v1 = *(const float4*)(src + kq + 16);
      As[i][kq + 0] = v0.x; As[i][kq + 1] = v0.y;
      As[i][kq + 2] = v0.z; As[i][kq + 3] = v0.w;
      As[i][kq + 16] = v1.x; As[i][kq + 17] = v1.y;
      As[i][kq + 18] = v1.z; As[i][kq + 19] = v1.w;
    }
    // stage B (weights, transposed into [k][g])
    {
      const int goff = tid >> 3;         // 0..31
      const int kq = (tid & 7) * 4;      // 0..28
      for (int gp = 0; gp < 128; gp += 32) {
        const float* src = Wih + (size_t)(n0 + goff + gp) * D + k0 + kq;
        float4 v = *(const float4*)src;
        Bs[kq + 0][goff + gp] = v.x;
        Bs[kq + 1][goff + gp] = v.y;
        Bs[kq + 2][goff + gp] = v.z;
        Bs[kq + 3][goff + gp] = v.w;
      }
    }
    __syncthreads();
    const int r0 = ty * 4;
#pragma unroll 4
    for (int k = 0; k < 32; ++k) {
      float a0 = As[r0 + 0][k], a1 = As[r0 + 1][k];
      float a2 = As[r0 + 2][k], a3 = As[r0 + 3][k];
#pragma unroll
      for (int cc = 0; cc < 8; ++cc) {
        float bv = Bs[k][tx + 16 * cc];
        acc[0][cc] = fmaf(a0, bv, acc[0][cc]);
        acc[1][cc] = fmaf(a1, bv, acc[1][cc]);
        acc[2][cc] = fmaf(a2, bv, acc[2][cc]);
        acc[3][cc] = fmaf(a3, bv, acc[3][cc]);
      }
    }
    __syncthreads();
  }
#pragma unroll
  for (int rr = 0; rr < 4; ++rr) {
    float* dst = gx + (size_t)(m0 + ty * 4 + rr) * G + n0;
#pragma unroll
    for (int cc = 0; cc < 8; ++cc) {
      int c = tx + 16 * cc;
      dst[c] = acc[rr][cc] + bih[n0 + c];
    }
  }
}

// ---------------------------------------------------------------------------
// Kernel C: persistent word-GRU scan. 64 WGs x 512 threads (8 waves, 2/SIMD).
// Thread t: d = t&255, kh = t>>8. Owns gate rows d (r), D+d (z), 2D+d (n),
// K-half [kh*128, kh*128+128): 3 x 64 half2 = 192 weight VGPRs (fits the
// 256 addressable-VGPR cap; no AGPR moves, no scratch).
// Per step: 16 b128 h-broadcasts feed 192 dot2; partial (aR,aZ,aN) written
// as one float4; updater thread d sums its k-half pair and applies gates.
// Barriers are LDS-only (no vmcnt drain) so gx prefetch + wo stores overlap.
// ---------------------------------------------------------------------------
__global__ __launch_bounds__(512, 2) void gru_scan_word(
    const float* __restrict__ gx,    // [NUTT][L][G] (includes b_ih)
    const float* __restrict__ Whh,   // [G][D]
    const float* __restrict__ bhh,   // [G]
    float* __restrict__ wo) {        // [NUTT][L][D]
  __shared__ uint4 h4[2][32];        // f16 h, double-buffered (512 B x2)
  __shared__ float4 pre[2][256];     // [khalf][d] = (aR,aZ,aN,-)

  const int t = threadIdx.x;
  const int b = blockIdx.x;
  const int d = t & 255;
  const int kh = t >> 8;             // 0: k<128, 1: k>=128

  // --- load this thread's 3 half-rows into VGPRs (f16) ---
  half2_t wr[64], wz[64], wn[64];
  {
    const float* rowR = Whh + (size_t)d * D + kh * 128;
    const float* rowZ = Whh + (size_t)(D + d) * D + kh * 128;
    const float* rowN = Whh + (size_t)(2 * D + d) * D + kh * 128;
#pragma unroll
    for (int c = 0; c < 32; ++c) {
      float4 v = *(const float4*)(rowR + 4 * c);
      wr[2 * c]     = half2_t{(_Float16)v.x, (_Float16)v.y};
      wr[2 * c + 1] = half2_t{(_Float16)v.z, (_Float16)v.w};
    }
#pragma unroll
    for (int c = 0; c < 32; ++c) {
      float4 v = *(const float4*)(rowZ + 4 * c);
      wz[2 * c]     = half2_t{(_Float16)v.x, (_Float16)v.y};
      wz[2 * c + 1] = half2_t{(_Float16)v.z, (_Float16)v.w};
    }
#pragma unroll
    for (int c = 0; c < 32; ++c) {
      float4 v = *(const float4*)(rowN + 4 * c);
      wn[2 * c]     = half2_t{(_Float16)v.x, (_Float16)v.y};
      wn[2 * c + 1] = half2_t{(_Float16)v.z, (_Float16)v.w};
    }
  }

  float bR = 0.0f, bZ = 0.0f, bN = 0.0f;
  float gr = 0.0f, gz = 0.0f, gn = 0.0f;
  const float* gxb = gx + (size_t)b * L * G;
  if (t < 256) {
    bR = bhh[d]; bZ = bhh[D + d]; bN = bhh[2 * D + d];
    gr = gxb[d]; gz = gxb[D + d]; gn = gxb[2 * D + d];
  }
  if (t < 32) h4[0][t] = uint4{0u, 0u, 0u, 0u};
  float hprev = 0.0f;
  float* wob = wo + (size_t)b * L * D;
  __syncthreads();

  for (int ts = 0; ts < L; ++ts) {
    const int cur = ts & 1;
    const uint4* hv = &h4[cur][kh * 16];
    float aR = 0.0f, aZ = 0.0f, aN = 0.0f;
#pragma unroll
    for (int c = 0; c < 16; ++c) {   // 1 b128 broadcast -> 12 dot2
      uint4 v = hv[c];
      half2_t h0 = u2h(v.x), h1 = u2h(v.y), h2 = u2h(v.z), h3 = u2h(v.w);
      aR = fdot2(wr[4 * c + 0], h0, aR);
      aZ = fdot2(wz[4 * c + 0], h0, aZ);
      aN = fdot2(wn[4 * c + 0], h0, aN);
      aR = fdot2(wr[4 * c + 1], h1, aR);
      aZ = fdot2(wz[4 * c + 1], h1, aZ);
      aN = fdot2(wn[4 * c + 1], h1, aN);
      aR = fdot2(wr[4 * c + 2], h2, aR);
      aZ = fdot2(wz[4 * c + 2], h2, aZ);
      aN = fdot2(wn[4 * c + 2], h2, aN);
      aR = fdot2(wr[4 * c + 3], h3, aR);
      aZ = fdot2(wz[4 * c + 3], h3, aZ);
      aN = fdot2(wn[4 * c + 3], h3, aN);
    }
    pre[kh][d] = float4{aR, aZ, aN, 0.0f};
    lds_barrier();

    if (t < 256) {
      float4 pa = pre[0][d];
      float4 pb = pre[1][d];
      float r = sigm(gr + pa.x + pb.x + bR);
      float z = sigm(gz + pa.y + pb.y + bZ);
      float n = tanh_f(gn + r * (pa.z + pb.z + bN));
      float hn = fmaf(z, hprev - n, n);        // (1-z)*n + z*h
      hprev = hn;
      reinterpret_cast<_Float16*>(h4[cur ^ 1])[d] = (_Float16)hn;
      wob[(size_t)ts * D + d] = hn;
      const int tn = (ts + 1 < L) ? ts + 1 : ts;
      const float* gxn = gxb + (size_t)tn * G;
      gr = gxn[d]; gz = gxn[D + d]; gn = gxn[2 * D + d];
    }
    lds_barrier();
  }
}

// ---------------------------------------------------------------------------
// Kernel D: attention pool over word_out -> utt[64][256]
// ---------------------------------------------------------------------------
__global__ __launch_bounds__(256) void attn_pool_word(
    const float* __restrict__ wo, const float* __restrict__ uaw,
    float* __restrict__ utt) {
  __shared__ float wsh[D];
  __shared__ float lg[L];
  __shared__ float red[8];
  const int tid = threadIdx.x, b = blockIdx.x;
  wsh[tid] = uaw[tid];
  __syncthreads();

  const int wid = tid >> 6, lane = tid & 63;
  const float* base = wo + (size_t)b * L * D;
  for (int t = wid; t < L; t += 4) {
    const float* row = base + (size_t)t * D;
    float p = 0.0f;
#pragma unroll
    for (int j = 0; j < 4; ++j) p = fmaf(row[lane + 64 * j], wsh[lane + 64 * j], p);
#pragma unroll
    for (int off = 32; off; off >>= 1) p += __shfl_down(p, off);
    if (lane == 0) lg[t] = p;                  // ua_b cancels in softmax
  }
  __syncthreads();

  float m = fmaxf(lg[tid], lg[tid + 256]);
#pragma unroll
  for (int off = 32; off; off >>= 1) m = fmaxf(m, __shfl_down(m, off));
  if (lane == 0) red[wid] = m;
  __syncthreads();
  m = fmaxf(fmaxf(red[0], red[1]), fmaxf(red[2], red[3]));

  float e0 = __expf(lg[tid] - m), e1 = __expf(lg[tid + 256] - m);
  float s = e0 + e1;
#pragma unroll
  for (int off = 32; off; off >>= 1) s += __shfl_down(s, off);
  if (lane == 0) red[4 + wid] = s;
  __syncthreads();
  s = red[4] + red[5] + red[6] + red[7];
  float inv = 1.0f / s;
  lg[tid] = e0 * inv;
  lg[tid + 256] = e1 * inv;
  __syncthreads();

  float acc = 0.0f;
#pragma unroll 4
  for (int t = 0; t < L; ++t) acc = fmaf(lg[t], base[(size_t)t * D + tid], acc);
  utt[(size_t)b * D + tid] = acc;
}

// ---------------------------------------------------------------------------
// Kernel E: sentence GRU (T=1, h0=0) -> dialog_vec = (1-z)*n
// ---------------------------------------------------------------------------
__global__ __launch_bounds__(256) void sent_kernel(
    const float* __restrict__ utt, const float* __restrict__ Wih,
    const float* __restrict__ bih, const float* __restrict__ bhh,
    float* __restrict__ out) {
  __shared__ float u[D];
  const int d = threadIdx.x, b = blockIdx.x;
  u[d] = utt[(size_t)b * D + d];
  __syncthreads();

  const float* wr = Wih + (size_t)d * D;
  const float* wz = Wih + (size_t)(D + d) * D;
  const float* wn = Wih + (size_t)(2 * D + d) * D;
  float ar = 0.0f, az = 0.0f, an = 0.0f;
  for (int k = 0; k < D; k += 4) {
    float4 vr = *(const float4*)(wr + k);
    float4 vz = *(const float4*)(wz + k);
    float4 vn = *(const float4*)(wn + k);
    float u0 = u[k], u1 = u[k + 1], u2 = u[k + 2], u3 = u[k + 3];
    ar += vr.x * u0 + vr.y * u1 + vr.z * u2 + vr.w * u3;
    az += vz.x * u0 + vz.y * u1 + vz.z * u2 + vz.w * u3;
    an += vn.x * u0 + vn.y * u1 + vn.z * u2 + vn.w * u3;
  }
  float xr = ar + bih[d];
  float xz = az + bih[D + d];
  float xn = an + bih[2 * D + d];
  float r = sigm(xr + bhh[d]);
  float z = sigm(xz + bhh[D + d]);
  float n = tanh_f(xn + r * bhh[2 * D + d]);
  out[(size_t)b * D + d] = (1.0f - z) * n;
}

// ---------------------------------------------------------------------------
extern "C" void kernel_launch(void* const* d_in, const int* in_sizes, int n_in,
                              void* d_out, int out_size, void* d_ws, size_t ws_size,
                              hipStream_t stream) {
  const int* tokens    = (const int*)d_in[0];
  const float* embed   = (const float*)d_in[1];
  const float* wg_Wih  = (const float*)d_in[2];
  const float* wg_Whh  = (const float*)d_in[3];
  const float* wg_bih  = (const float*)d_in[4];
  const float* wg_bhh  = (const float*)d_in[5];
  const float* ua_w    = (const float*)d_in[6];
  // d_in[7] ua_b: softmax shift-invariant -> unused
  const float* sg_Wih  = (const float*)d_in[8];
  // d_in[9] sg_Whh: h0 == 0 -> unused
  const float* sg_bih  = (const float*)d_in[10];
  const float* sg_bhh  = (const float*)d_in[11];
  // d_in[12..13] da_w/da_b: softmax over T=1 -> unused
  float* out = (float*)d_out;

  char* ws = (char*)d_ws;
  float* gx  = (float*)ws;                                     // 96 MB
  float* wo  = (float*)(ws + (size_t)NUTT * L * G * 4);        // 32 MB
  float* utt = (float*)(ws + (size_t)NUTT * L * G * 4
                           + (size_t)NUTT * L * D * 4);        // 64 KB

  dim3 gB(512, 6);
  gx_gemm<<<gB, 256, 0, stream>>>(tokens, embed, wg_Wih, wg_bih, gx);
  gru_scan_word<<<NUTT, 512, 0, stream>>>(gx, wg_Whh, wg_bhh, wo);
  attn_pool_word<<<NUTT, 256, 0, stream>>>(wo, ua_w, utt);
  sent_kernel<<<NUTT, 256, 0, stream>>>(utt, sg_Wih, sg_bih, sg_bhh, out);
}